// Round 11
// baseline (1285.465 us; speedup 1.0000x reference)
//
#include <hip/hip_runtime.h>
#include <math.h>

#define NN 100000
#define EE 1600000
#define GG 64
#define HH 128
#define LL 4
#define CCLS 16
#define NC 100000
#define NB 49    // dst buckets of 2048 nodes
#define LDK 40   // padded LDS row stride (bf16 elems) for 32-wide K tiles
#define LDA2 136 // padded LDS row stride for full-K (128) A tiles

typedef __attribute__((ext_vector_type(8))) short bf16x8;
typedef __attribute__((ext_vector_type(4))) float f32x4;

__device__ __forceinline__ unsigned short f2bf(float x) {
  union { float f; unsigned int u; } v; v.f = x;
  unsigned int r = v.u + 0x7fffu + ((v.u >> 16) & 1u);
  return (unsigned short)(r >> 16);
}
__device__ __forceinline__ float bl(unsigned u) {
  union { unsigned u; float f; } v; v.u = u << 16; return v.f;
}
__device__ __forceinline__ float bh(unsigned u) {
  union { unsigned u; float f; } v; v.u = u & 0xffff0000u; return v.f;
}

// ---------------- CSR build ----------------
__global__ void hist_kernel(const int* __restrict__ dst, int* __restrict__ cnt, int E) {
  int e = blockIdx.x * 256 + threadIdx.x;
  if (e < E) atomicAdd(&cnt[dst[e]], 1);
}

__global__ __launch_bounds__(256) void scan_p1(const int* __restrict__ cnt,
                                               int* __restrict__ bsum, int n) {
  __shared__ int red[256];
  int tid = threadIdx.x;
  int base = blockIdx.x * 1024 + tid * 4;
  int s = 0;
  if (base + 3 < n) {
    int4 v = *(const int4*)(cnt + base);
    s = v.x + v.y + v.z + v.w;
  } else {
    for (int i = 0; i < 4; ++i) if (base + i < n) s += cnt[base + i];
  }
  red[tid] = s;
  __syncthreads();
  for (int st = 128; st >= 1; st >>= 1) {
    if (tid < st) red[tid] += red[tid + st];
    __syncthreads();
  }
  if (tid == 0) bsum[blockIdx.x] = red[0];
}

__global__ void scan_p2(int* __restrict__ bsum, int* __restrict__ rowptr,
                        int* __restrict__ bcursor, int nb, int n) {
  __shared__ int buf[128];
  int tid = threadIdx.x;
  int v = (tid < nb) ? bsum[tid] : 0;
  buf[tid] = v;
  __syncthreads();
  for (int off = 1; off < 128; off <<= 1) {
    int t = (tid >= off) ? buf[tid - off] : 0;
    __syncthreads();
    buf[tid] += t;
    __syncthreads();
  }
  if (tid < nb) bsum[tid] = buf[tid] - v;
  if (tid == 127) rowptr[n] = buf[127];
  __syncthreads();
  if (tid < NB) bcursor[tid] = bsum[2 * tid];
}

__global__ __launch_bounds__(256) void scan_p3(const int* __restrict__ cnt,
                                               const int* __restrict__ bsum,
                                               int* __restrict__ rowptr,
                                               int* __restrict__ cursor, int n) {
  __shared__ int red[256];
  int tid = threadIdx.x;
  int base = blockIdx.x * 1024 + tid * 4;
  int v[4] = {0, 0, 0, 0};
  if (base + 3 < n) {
    int4 t = *(const int4*)(cnt + base);
    v[0] = t.x; v[1] = t.y; v[2] = t.z; v[3] = t.w;
  } else {
    for (int i = 0; i < 4; ++i) if (base + i < n) v[i] = cnt[base + i];
  }
  int s = v[0] + v[1] + v[2] + v[3];
  red[tid] = s;
  __syncthreads();
  for (int off = 1; off < 256; off <<= 1) {
    int t = (tid >= off) ? red[tid - off] : 0;
    __syncthreads();
    red[tid] += t;
    __syncthreads();
  }
  int run = bsum[blockIdx.x] + red[tid] - s;
  int4 o;
  o.x = run; o.y = run + v[0]; o.z = o.y + v[1]; o.w = o.z + v[2];
  if (base + 3 < n) {
    *(int4*)(rowptr + base) = o;
    *(int4*)(cursor + base) = o;
  } else {
    int oo[4] = {o.x, o.y, o.z, o.w};
    for (int i = 0; i < 4; ++i)
      if (base + i < n) { rowptr[base + i] = oo[i]; cursor[base + i] = oo[i]; }
  }
}

// Counting-sort pass 1: partition edges into 49 dst-bucket pair regions.
__global__ __launch_bounds__(256) void partition_kernel(const int* __restrict__ src,
                                                        const int* __restrict__ dst,
                                                        int* __restrict__ bcursor,
                                                        int2* __restrict__ pairs, int E) {
  __shared__ int sS[4096];
  __shared__ int sD[4096];
  __shared__ int hist[NB];
  __shared__ int base[NB];
  int tid = threadIdx.x;
  int base_e = blockIdx.x * 4096;
  int cnt = min(4096, E - base_e);
  if (tid < NB) hist[tid] = 0;
  for (int i = tid * 4; i < cnt; i += 1024) {
    if (i + 3 < cnt) {
      *(int4*)(sS + i) = *(const int4*)(src + base_e + i);
      *(int4*)(sD + i) = *(const int4*)(dst + base_e + i);
    } else {
      for (int k = i; k < cnt; ++k) { sS[k] = src[base_e + k]; sD[k] = dst[base_e + k]; }
    }
  }
  __syncthreads();
  for (int i = tid; i < cnt; i += 256) atomicAdd(&hist[sD[i] >> 11], 1);
  __syncthreads();
  if (tid < NB) {
    base[tid] = atomicAdd(&bcursor[tid], hist[tid]);
    hist[tid] = 0;
  }
  __syncthreads();
  for (int i = tid; i < cnt; i += 256) {
    int d = sD[i];
    int b = d >> 11;
    int off = atomicAdd(&hist[b], 1);
    pairs[base[b] + off] = make_int2(sS[i], d);
  }
}

// Counting-sort pass 2: per-bucket scatter to final CSR positions.
__global__ __launch_bounds__(256) void scatter_csr(const int2* __restrict__ pairs,
                                                   const int* __restrict__ rowptr,
                                                   int* __restrict__ cursor,
                                                   int* __restrict__ csr_src) {
  int b = blockIdx.x % 56;
  int slice = blockIdx.x / 56;
  if (b >= NB) return;
  int start = rowptr[b * 2048];
  int endn = min((b + 1) * 2048, NN);
  int end = rowptr[endn];
  for (int i = start + slice * 256 + threadIdx.x; i < end; i += 8 * 256) {
    int2 p = pairs[i];
    int pos = atomicAdd(&cursor[p.y], 1);
    csr_src[pos] = p.x;
  }
}

// ---------------- converts ----------------
__global__ void f2b4_kernel(const float* __restrict__ in, unsigned short* __restrict__ out, int n4) {
  int i = blockIdx.x * 256 + threadIdx.x;
  if (i >= n4) return;
  float4 v = ((const float4*)in)[i];
  unsigned short r[4] = {f2bf(v.x), f2bf(v.y), f2bf(v.z), f2bf(v.w)};
  *(uint2*)(out + (size_t)i * 4) = *(uint2*)r;
}

// merged: trunk W1/W2, epW1, epW2 — all to [N][K] bf16
__global__ void conv_weights(const float* __restrict__ cW1, const float* __restrict__ cW2,
                             unsigned short* __restrict__ WT1, unsigned short* __restrict__ WT2,
                             const float* __restrict__ epW1, unsigned short* __restrict__ W1T,
                             const float* __restrict__ epW2, unsigned short* __restrict__ W2T) {
  int idx = blockIdx.x * 256 + threadIdx.x;
  if (idx < LL * 16384) {
    int l = idx >> 14, r = idx & 16383, k = r >> 7, n = r & 127;
    WT1[l * 16384 + n * 128 + k] = f2bf(cW1[idx]);
    WT2[l * 16384 + n * 128 + k] = f2bf(cW2[idx]);
  } else if (idx < LL * 16384 + 262144) {
    int j = idx - LL * 16384;
    int k = j >> 8, n = j & 255;
    W1T[(size_t)n * 1024 + k] = f2bf(epW1[j]);
  } else if (idx < LL * 16384 + 262144 + 32768) {
    int j = idx - LL * 16384 - 262144;
    int k = j >> 7, n = j & 127;
    W2T[(size_t)n * 256 + k] = f2bf(epW2[j]);
  }
}

// ---------------- GIN aggregate: 16-lane subgroup per node, x8 unroll ----------------
__global__ void aggregate_bf16(const unsigned short* __restrict__ h16, int ld,
                               const int* __restrict__ rowptr,
                               const int* __restrict__ csr_src,
                               const float* __restrict__ ceps_l,
                               unsigned short* __restrict__ out, int n) {
  int wave = threadIdx.x >> 6;
  int lane = threadIdx.x & 63;
  int sub = lane >> 4;
  int li = lane & 15;
  int node = blockIdx.x * 16 + wave * 4 + sub;
  if (node >= n) return;
  int c8 = li * 8;
  float eps1 = 1.0f + *ceps_l;
  float acc[8] = {};
  int b = rowptr[node], e = rowptr[node + 1];
  int j = b;
  for (; j + 8 <= e; j += 8) {
    uint4 u[8];
#pragma unroll
    for (int t = 0; t < 8; ++t) {
      int s = csr_src[j + t];
      u[t] = *(const uint4*)(h16 + (size_t)s * ld + c8);
    }
#pragma unroll
    for (int t = 0; t < 8; ++t) {
      acc[0] += bl(u[t].x); acc[1] += bh(u[t].x);
      acc[2] += bl(u[t].y); acc[3] += bh(u[t].y);
      acc[4] += bl(u[t].z); acc[5] += bh(u[t].z);
      acc[6] += bl(u[t].w); acc[7] += bh(u[t].w);
    }
  }
  for (; j < e; ++j) {
    int s = csr_src[j];
    uint4 u = *(const uint4*)(h16 + (size_t)s * ld + c8);
    acc[0] += bl(u.x); acc[1] += bh(u.x);
    acc[2] += bl(u.y); acc[3] += bh(u.y);
    acc[4] += bl(u.z); acc[5] += bh(u.z);
    acc[6] += bl(u.w); acc[7] += bh(u.w);
  }
  uint4 hu = *(const uint4*)(h16 + (size_t)node * ld + c8);
  acc[0] = fmaf(eps1, bl(hu.x), acc[0]); acc[1] = fmaf(eps1, bh(hu.x), acc[1]);
  acc[2] = fmaf(eps1, bl(hu.y), acc[2]); acc[3] = fmaf(eps1, bh(hu.y), acc[3]);
  acc[4] = fmaf(eps1, bl(hu.z), acc[4]); acc[5] = fmaf(eps1, bh(hu.z), acc[5]);
  acc[6] = fmaf(eps1, bl(hu.w), acc[6]); acc[7] = fmaf(eps1, bh(hu.w), acc[7]);
  unsigned short o[8];
#pragma unroll
  for (int i = 0; i < 8; ++i) o[i] = f2bf(acc[i]);
  *(uint4*)(out + (size_t)node * 128 + c8) = *(uint4*)o;
}

// ---------------- fused trunk layer (B register-prefetch) ----------------
__global__ __launch_bounds__(256) void trunk_fused(
    const unsigned short* __restrict__ A16,
    const unsigned short* __restrict__ W1T, const float* __restrict__ b1,
    const unsigned short* __restrict__ W2T, const float* __restrict__ b2,
    float* __restrict__ bnsum, float* __restrict__ bnsumsq,
    unsigned short* __restrict__ C16, int M) {
  __shared__ unsigned short As[128 * LDA2];
  __shared__ unsigned short Bs[128 * LDK];
  const int tid = threadIdx.x;
  const int bm = blockIdx.x * 128;
  const int lane = tid & 63;
  const int wave = tid >> 6;
  const int wr = (wave >> 1) << 6;
  const int wc = (wave & 1) << 6;
  const int ar = tid >> 1;
  const int ah = (tid & 1) << 4;
  int gra = bm + ar; if (gra >= M) gra = M - 1;
  const unsigned short* Arow = A16 + (size_t)gra * 128;
  const int mrow = lane & 15;
  const int kq = (lane >> 4) << 3;
  f32x4 acc[4][4] = {};

#pragma unroll
  for (int ks = 0; ks < 4; ++ks) {
    const int k0 = ks << 5;
    const uint4* s = (const uint4*)(Arow + k0 + ah);
    *(uint4*)(As + ar * LDA2 + k0 + ah) = s[0];
    *(uint4*)(As + ar * LDA2 + k0 + ah + 8) = s[1];
  }
  uint4 p0 = *(const uint4*)(W1T + (size_t)ar * 128 + ah);
  uint4 p1 = *(const uint4*)(W1T + (size_t)ar * 128 + ah + 8);
  for (int ks = 0; ks < 4; ++ks) {
    const int k0 = ks << 5;
    *(uint4*)(Bs + ar * LDK + ah) = p0;
    *(uint4*)(Bs + ar * LDK + ah + 8) = p1;
    __syncthreads();
    if (ks < 3) {
      p0 = *(const uint4*)(W1T + (size_t)ar * 128 + k0 + 32 + ah);
      p1 = *(const uint4*)(W1T + (size_t)ar * 128 + k0 + 32 + ah + 8);
    }
    bf16x8 af[4], bfv[4];
#pragma unroll
    for (int t = 0; t < 4; ++t)
      af[t] = *(const bf16x8*)(As + (wr + t * 16 + mrow) * LDA2 + k0 + kq);
#pragma unroll
    for (int t = 0; t < 4; ++t)
      bfv[t] = *(const bf16x8*)(Bs + (wc + t * 16 + mrow) * LDK + kq);
#pragma unroll
    for (int mt = 0; mt < 4; ++mt)
#pragma unroll
      for (int nt = 0; nt < 4; ++nt)
        acc[mt][nt] = __builtin_amdgcn_mfma_f32_16x16x32_bf16(af[mt], bfv[nt], acc[mt][nt], 0, 0, 0);
    __syncthreads();
  }
  const int crow = (lane >> 4) << 2;
  const int ccol = lane & 15;
#pragma unroll
  for (int nt = 0; nt < 4; ++nt) {
    int c = wc + nt * 16 + ccol;
    float bz = b1[c];
#pragma unroll
    for (int mt = 0; mt < 4; ++mt) {
      int rl = wr + mt * 16 + crow;
#pragma unroll
      for (int i = 0; i < 4; ++i)
        As[(rl + i) * LDA2 + c] = f2bf(fmaxf(acc[mt][nt][i] + bz, 0.f));
    }
  }
#pragma unroll
  for (int mt = 0; mt < 4; ++mt)
#pragma unroll
    for (int nt = 0; nt < 4; ++nt)
      acc[mt][nt] = (f32x4){0.f, 0.f, 0.f, 0.f};
  p0 = *(const uint4*)(W2T + (size_t)ar * 128 + ah);
  p1 = *(const uint4*)(W2T + (size_t)ar * 128 + ah + 8);
  __syncthreads();
  for (int ks = 0; ks < 4; ++ks) {
    const int k0 = ks << 5;
    *(uint4*)(Bs + ar * LDK + ah) = p0;
    *(uint4*)(Bs + ar * LDK + ah + 8) = p1;
    __syncthreads();
    if (ks < 3) {
      p0 = *(const uint4*)(W2T + (size_t)ar * 128 + k0 + 32 + ah);
      p1 = *(const uint4*)(W2T + (size_t)ar * 128 + k0 + 32 + ah + 8);
    }
    bf16x8 af[4], bfv[4];
#pragma unroll
    for (int t = 0; t < 4; ++t)
      af[t] = *(const bf16x8*)(As + (wr + t * 16 + mrow) * LDA2 + k0 + kq);
#pragma unroll
    for (int t = 0; t < 4; ++t)
      bfv[t] = *(const bf16x8*)(Bs + (wc + t * 16 + mrow) * LDK + kq);
#pragma unroll
    for (int mt = 0; mt < 4; ++mt)
#pragma unroll
      for (int nt = 0; nt < 4; ++nt)
        acc[mt][nt] = __builtin_amdgcn_mfma_f32_16x16x32_bf16(af[mt], bfv[nt], acc[mt][nt], 0, 0, 0);
    __syncthreads();
  }
#pragma unroll
  for (int nt = 0; nt < 4; ++nt) {
    int c = wc + nt * 16 + ccol;
    float bz = b2[c];
    float s = 0.f, q = 0.f;
#pragma unroll
    for (int mt = 0; mt < 4; ++mt) {
      int rbase = bm + wr + mt * 16 + crow;
#pragma unroll
      for (int i = 0; i < 4; ++i) {
        int r = rbase + i;
        if (r < M) {
          float v = fmaxf(acc[mt][nt][i] + bz, 0.f);
          C16[(size_t)r * 128 + c] = f2bf(v);
          s += v; q += v * v;
        }
      }
    }
    s += __shfl_xor(s, 16, 64);
    s += __shfl_xor(s, 32, 64);
    q += __shfl_xor(q, 16, 64);
    q += __shfl_xor(q, 32, 64);
    if (lane < 16) {
      atomicAdd(&bnsum[c], s);
      atomicAdd(&bnsumsq[c], q);
    }
  }
}

// ---------------- ep GEMM2: double-buffered LDS, one barrier per K-step ----------------
__global__ __launch_bounds__(256) void mfma_gemm_bt(
    const unsigned short* __restrict__ A16, int lda,
    const unsigned short* __restrict__ WT, int K,
    const float* __restrict__ bias,
    unsigned short* __restrict__ C16, int ldc, int M) {
  __shared__ unsigned short As[2][128 * LDK];
  __shared__ unsigned short Bs[2][128 * LDK];
  const int tid = threadIdx.x;
  const int bm = blockIdx.x * 128;
  const int bn = blockIdx.y * 128;
  const int lane = tid & 63;
  const int wave = tid >> 6;
  const int wr = (wave >> 1) << 6;
  const int wc = (wave & 1) << 6;
  f32x4 acc[4][4] = {};
  const int ar = tid >> 1;
  const int ah = (tid & 1) << 4;
  int gra = bm + ar; if (gra >= M) gra = M - 1;
  const unsigned short* Arow = A16 + (size_t)gra * lda;
  const unsigned short* Brow = WT + (size_t)(bn + ar) * K;
  const int mrow = lane & 15;
  const int kq = (lane >> 4) << 3;
  const int nks = K >> 5;

  {
    uint4 a0 = *(const uint4*)(Arow + ah);
    uint4 a1 = *(const uint4*)(Arow + ah + 8);
    uint4 b0 = *(const uint4*)(Brow + ah);
    uint4 b1 = *(const uint4*)(Brow + ah + 8);
    *(uint4*)(As[0] + ar * LDK + ah) = a0;
    *(uint4*)(As[0] + ar * LDK + ah + 8) = a1;
    *(uint4*)(Bs[0] + ar * LDK + ah) = b0;
    *(uint4*)(Bs[0] + ar * LDK + ah + 8) = b1;
  }
  __syncthreads();
  for (int ks = 0; ks < nks; ++ks) {
    const int cur = ks & 1, nxt = cur ^ 1;
    uint4 a0, a1, b0, b1;
    if (ks + 1 < nks) {
      const int k1 = (ks + 1) << 5;
      a0 = *(const uint4*)(Arow + k1 + ah);
      a1 = *(const uint4*)(Arow + k1 + ah + 8);
      b0 = *(const uint4*)(Brow + k1 + ah);
      b1 = *(const uint4*)(Brow + k1 + ah + 8);
    }
    bf16x8 af[4], bfv[4];
#pragma unroll
    for (int t = 0; t < 4; ++t)
      af[t] = *(const bf16x8*)(As[cur] + (wr + t * 16 + mrow) * LDK + kq);
#pragma unroll
    for (int t = 0; t < 4; ++t)
      bfv[t] = *(const bf16x8*)(Bs[cur] + (wc + t * 16 + mrow) * LDK + kq);
#pragma unroll
    for (int mt = 0; mt < 4; ++mt)
#pragma unroll
      for (int nt = 0; nt < 4; ++nt)
        acc[mt][nt] = __builtin_amdgcn_mfma_f32_16x16x32_bf16(af[mt], bfv[nt], acc[mt][nt], 0, 0, 0);
    if (ks + 1 < nks) {
      *(uint4*)(As[nxt] + ar * LDK + ah) = a0;
      *(uint4*)(As[nxt] + ar * LDK + ah + 8) = a1;
      *(uint4*)(Bs[nxt] + ar * LDK + ah) = b0;
      *(uint4*)(Bs[nxt] + ar * LDK + ah + 8) = b1;
      __syncthreads();
    }
  }
  const int crow = (lane >> 4) << 2;
  const int ccol = lane & 15;
#pragma unroll
  for (int nt = 0; nt < 4; ++nt) {
    int cbase = bn + wc + nt * 16 + ccol;
    float bz = bias[cbase];
#pragma unroll
    for (int mt = 0; mt < 4; ++mt) {
      int rbase = bm + wr + mt * 16 + crow;
#pragma unroll
      for (int i = 0; i < 4; ++i) {
        int r = rbase + i;
        if (r < M) C16[(size_t)r * ldc + cbase] = f2bf(fmaxf(acc[mt][nt][i] + bz, 0.f));
      }
    }
  }
}

// ep GEMM1: barrier-free streaming gather GEMM.
// Each lane loads its A-frag (16B of a gathered emb16 row) and B-frag (16B of
// W1T) DIRECTLY from global into MFMA operand registers; 1-step register
// prefetch; no LDS staging, no __syncthreads in the K-loop. Waves run as
// independent streams — latency hidden by per-wave vmcnt + cross-wave TLP.
__global__ __launch_bounds__(512) void ep_gemm1_stream(
    const unsigned short* __restrict__ emb16, const int* __restrict__ cand,
    const unsigned short* __restrict__ WT /*[256][1024]*/,
    const float* __restrict__ bias,
    unsigned short* __restrict__ C16 /*[M,256]*/, int M) {
  __shared__ int sN0[128];
  __shared__ int sN1[128];
  const int tid = threadIdx.x;
  const int bm = blockIdx.x * 128;
  const int lane = tid & 63;
  const int wave = tid >> 6;
  const int wr = (wave >> 2) << 6;   // 0 / 64
  const int wc = (wave & 3) << 6;    // 0 / 64 / 128 / 192
  const int mrow = lane & 15;
  const int kq = (lane >> 4) << 3;
  if (tid < 128) {
    int g = bm + tid; if (g >= M) g = M - 1;
    sN0[tid] = cand[g];
    sN1[tid] = cand[NC + g];
  }
  __syncthreads();
  int n0[4], n1[4];
  const unsigned short* brow[4];
#pragma unroll
  for (int mt = 0; mt < 4; ++mt) {
    int r = wr + mt * 16 + mrow;
    n0[mt] = sN0[r];
    n1[mt] = sN1[r];
  }
#pragma unroll
  for (int nt = 0; nt < 4; ++nt)
    brow[nt] = WT + (size_t)(wc + nt * 16 + mrow) * 1024 + kq;
  f32x4 acc[4][4] = {};
  bf16x8 afP[4], bfP[4];
#pragma unroll
  for (int mt = 0; mt < 4; ++mt)
    afP[mt] = *(const bf16x8*)(emb16 + (size_t)n0[mt] * 512 + kq);
#pragma unroll
  for (int nt = 0; nt < 4; ++nt)
    bfP[nt] = *(const bf16x8*)(brow[nt]);
  for (int ks = 0; ks < 32; ++ks) {
    bf16x8 af[4], bf[4];
#pragma unroll
    for (int t = 0; t < 4; ++t) { af[t] = afP[t]; bf[t] = bfP[t]; }
    if (ks < 31) {
      const int k1 = (ks + 1) << 5;
      const int col = (k1 & 511) + kq;
      const bool first = (k1 < 512);
#pragma unroll
      for (int mt = 0; mt < 4; ++mt) {
        int node = first ? n0[mt] : n1[mt];
        afP[mt] = *(const bf16x8*)(emb16 + (size_t)node * 512 + col);
      }
#pragma unroll
      for (int nt = 0; nt < 4; ++nt)
        bfP[nt] = *(const bf16x8*)(brow[nt] + k1);
    }
#pragma unroll
    for (int mt = 0; mt < 4; ++mt)
#pragma unroll
      for (int nt = 0; nt < 4; ++nt)
        acc[mt][nt] = __builtin_amdgcn_mfma_f32_16x16x32_bf16(af[mt], bf[nt], acc[mt][nt], 0, 0, 0);
  }
  const int crow = (lane >> 4) << 2;
  const int ccol = lane & 15;
#pragma unroll
  for (int nt = 0; nt < 4; ++nt) {
    int cbase = wc + nt * 16 + ccol;
    float bz = bias[cbase];
#pragma unroll
    for (int mt = 0; mt < 4; ++mt) {
      int rbase = bm + wr + mt * 16 + crow;
#pragma unroll
      for (int i = 0; i < 4; ++i) {
        int r = rbase + i;
        if (r < M) C16[(size_t)r * 256 + cbase] = f2bf(fmaxf(acc[mt][nt][i] + bz, 0.f));
      }
    }
  }
}

// ---------------- BatchNorm apply ----------------
__global__ void bn_apply_bf16(const unsigned short* __restrict__ z,
                              const float* __restrict__ sum, const float* __restrict__ sumsq,
                              const float* __restrict__ gamma, const float* __restrict__ beta,
                              unsigned short* __restrict__ out, int n) {
  int idx = blockIdx.x * 256 + threadIdx.x;
  if (idx >= n * 16) return;
  int r = idx >> 4, c8 = (idx & 15) << 3;
  uint4 v = *(const uint4*)(z + (size_t)r * 128 + c8);
  float f[8] = {bl(v.x), bh(v.x), bl(v.y), bh(v.y), bl(v.z), bh(v.z), bl(v.w), bh(v.w)};
  const float inv_n = 1.0f / (float)NN;
  unsigned short o[8];
#pragma unroll
  for (int j = 0; j < 8; ++j) {
    int c = c8 + j;
    float mu = sum[c] * inv_n;
    float var = sumsq[c] * inv_n - mu * mu;
    float sc = rsqrtf(var + 1e-5f) * gamma[c];
    o[j] = f2bf((f[j] - mu) * sc + beta[c]);
  }
  *(uint4*)(out + (size_t)r * 512 + c8) = *(uint4*)o;
}

// ---------------- pooling ----------------
__global__ void bounds_kernel(const int* __restrict__ batch, int* __restrict__ gstart, int n) {
  int g = threadIdx.x;
  if (g > GG) return;
  int lo = 0, hi = n;
  while (lo < hi) {
    int mid = (lo + hi) >> 1;
    if (batch[mid] < g) lo = mid + 1; else hi = mid;
  }
  gstart[g] = lo;
}

__global__ __launch_bounds__(256) void pool_bf16(const unsigned short* __restrict__ emb16,
                                                 const int* __restrict__ gstart,
                                                 float* __restrict__ gsum) {
  int g = blockIdx.x;
  int chunk = blockIdx.y;
  int c2 = threadIdx.x * 2;
  int s = gstart[g], e = gstart[g + 1];
  int len = e - s;
  int per = (len + 7) >> 3;
  int r0 = s + chunk * per;
  int r1 = min(r0 + per, e);
  float ax = 0.f, ay = 0.f;
  for (int r = r0; r < r1; ++r) {
    unsigned u = *(const unsigned*)(emb16 + (size_t)r * 512 + c2);
    ax += bl(u); ay += bh(u);
  }
  if (r1 > r0) {
    atomicAdd(&gsum[g * 512 + c2], ax);
    atomicAdd(&gsum[g * 512 + c2 + 1], ay);
  }
}

// ---------------- fused node classifier ----------------
__global__ __launch_bounds__(256) void nc_fused(
    const float* __restrict__ gsum, const int* __restrict__ gstart,
    const float* __restrict__ W1, const float* __restrict__ b1,
    const float* __restrict__ W2, const float* __restrict__ b2,
    const float* __restrict__ W3, const float* __restrict__ b3,
    const float* __restrict__ W4, const float* __restrict__ b4,
    float* __restrict__ out) {
  __shared__ float row[512];
  __shared__ float t1[256];
  __shared__ float t2[128];
  __shared__ float t3s[128];
  __shared__ float lg[16];
  int g = blockIdx.x;
  int tid = threadIdx.x;
  float inv = 1.0f / fmaxf((float)(gstart[g + 1] - gstart[g]), 1.0f);
  row[tid] = gsum[g * 512 + tid] * inv;
  row[tid + 256] = gsum[g * 512 + tid + 256] * inv;
  __syncthreads();
  {
    float acc = b1[tid];
#pragma unroll 8
    for (int k = 0; k < 512; ++k) acc = fmaf(row[k], W1[k * 256 + tid], acc);
    t1[tid] = fmaxf(acc, 0.f);
  }
  __syncthreads();
  if (tid < 128) {
    float acc = b2[tid];
#pragma unroll 8
    for (int k = 0; k < 256; ++k) acc = fmaf(t1[k], W2[k * 128 + tid], acc);
    t2[tid] = fmaxf(acc, 0.f);
  }
  __syncthreads();
  if (tid < 128) {
    float acc = b3[tid];
#pragma unroll 8
    for (int k = 0; k < 128; ++k) acc = fmaf(t2[k], W3[k * 128 + tid], acc);
    t3s[tid] = fmaxf(acc, 0.f);
  }
  __syncthreads();
  if (tid < 16) {
    float acc = b4[tid];
#pragma unroll 8
    for (int k = 0; k < 128; ++k) acc = fmaf(t3s[k], W4[k * 16 + tid], acc);
    lg[tid] = acc;
  }
  __syncthreads();
  if (tid < 16) {
    float v = lg[tid];
    float m = v;
    for (int j = 0; j < 16; ++j) m = fmaxf(m, lg[j]);
    float s = 0.f;
    for (int j = 0; j < 16; ++j) s += expf(lg[j] - m);
    out[g * 16 + tid] = v - m - logf(s);
  }
}

__global__ void ep_final_bf16(const unsigned short* __restrict__ C2, const float* __restrict__ w,
                              const float* __restrict__ b3, float* __restrict__ out, int M) {
  int row = blockIdx.x * 4 + (threadIdx.x >> 6);
  if (row >= M) return;
  int lane = threadIdx.x & 63;
  int c2 = lane * 2;
  unsigned u = *(const unsigned*)(C2 + (size_t)row * 128 + c2);
  float2 wv = *(const float2*)(w + c2);
  float s = bl(u) * wv.x + bh(u) * wv.y;
  for (int off = 32; off >= 1; off >>= 1) s += __shfl_down(s, off, 64);
  if (lane == 0) out[row] = 1.f / (1.f + expf(-(s + b3[0])));
}

// ---------------- launch ----------------
extern "C" void kernel_launch(void* const* d_in, const int* in_sizes, int n_in,
                              void* d_out, int out_size, void* d_ws, size_t ws_size,
                              hipStream_t stream) {
  const float* x = (const float*)d_in[0];
  const int* edge_index = (const int*)d_in[1];
  const int* batch = (const int*)d_in[2];
  const int* cand = (const int*)d_in[3];
  const float* cW1 = (const float*)d_in[4];
  const float* cb1 = (const float*)d_in[5];
  const float* cW2 = (const float*)d_in[6];
  const float* cb2 = (const float*)d_in[7];
  const float* cgamma = (const float*)d_in[8];
  const float* cbeta = (const float*)d_in[9];
  const float* ceps = (const float*)d_in[10];
  const float* ncW1 = (const float*)d_in[11];
  const float* ncb1 = (const float*)d_in[12];
  const float* ncW2 = (const float*)d_in[13];
  const float* ncb2 = (const float*)d_in[14];
  const float* ncW3 = (const float*)d_in[15];
  const float* ncb3 = (const float*)d_in[16];
  const float* ncW4 = (const float*)d_in[17];
  const float* ncb4 = (const float*)d_in[18];
  const float* epW1 = (const float*)d_in[19];
  const float* epb1 = (const float*)d_in[20];
  const float* epW2 = (const float*)d_in[21];
  const float* epb2 = (const float*)d_in[22];
  const float* epW3 = (const float*)d_in[23];
  const float* epb3 = (const float*)d_in[24];

  char* ws = (char*)d_ws;
  size_t off = 0;
  auto alloc = [&](size_t bytes) -> void* {
    off = (off + 255) & ~(size_t)255;
    void* p = ws + off;
    off += bytes;
    return p;
  };
  // zero zone: cnt | bnsum | bnsumsq | gsum
  size_t zz_bytes = (size_t)NN * 4 + 512 * 4 + 512 * 4 + (size_t)GG * 512 * 4;
  char* zz = (char*)alloc(zz_bytes);
  int* cnt = (int*)zz;
  float* bnsum = (float*)(zz + (size_t)NN * 4);
  float* bnsumsq = bnsum + 512;
  float* gsum = bnsumsq + 512;
  int* rowptr = (int*)alloc((size_t)(NN + 1) * 4);
  int* cursor = (int*)alloc((size_t)NN * 4);
  int* csr_src = (int*)alloc((size_t)EE * 4);
  int2* pairs = (int2*)alloc((size_t)EE * 8);
  int* bsum = (int*)alloc(128 * 4);
  int* bcursor = (int*)alloc(64 * 4);
  unsigned short* x16 = (unsigned short*)alloc((size_t)NN * 128 * 2);
  unsigned short* g16a = (unsigned short*)alloc((size_t)NN * 128 * 2);
  unsigned short* emb16 = (unsigned short*)alloc((size_t)NN * 512 * 2);
  unsigned short* C1 = (unsigned short*)alloc((size_t)NC * 256 * 2);
  unsigned short* C2 = (unsigned short*)alloc((size_t)NC * 128 * 2);
  unsigned short* WT1 = (unsigned short*)alloc((size_t)LL * 16384 * 2);
  unsigned short* WT2 = (unsigned short*)alloc((size_t)LL * 16384 * 2);
  unsigned short* W1T = (unsigned short*)alloc((size_t)1024 * 256 * 2);
  unsigned short* W2T = (unsigned short*)alloc((size_t)256 * 128 * 2);
  int* gstart = (int*)alloc(65 * 4);

  const int* esrc = edge_index;
  const int* edst = edge_index + EE;
  const int nblk = (NN + 1023) / 1024;   // 98
  const int nech = (EE + 4095) / 4096;   // 391

  hipMemsetAsync(zz, 0, zz_bytes, stream);
  hist_kernel<<<(EE + 255) / 256, 256, 0, stream>>>(edst, cnt, EE);
  scan_p1<<<nblk, 256, 0, stream>>>(cnt, bsum, NN);
  scan_p2<<<1, 128, 0, stream>>>(bsum, rowptr, bcursor, nblk, NN);
  scan_p3<<<nblk, 256, 0, stream>>>(cnt, bsum, rowptr, cursor, NN);
  partition_kernel<<<nech, 256, 0, stream>>>(esrc, edst, bcursor, pairs, EE);
  scatter_csr<<<56 * 8, 256, 0, stream>>>(pairs, rowptr, cursor, csr_src);
  f2b4_kernel<<<(NN * 128 / 4 + 255) / 256, 256, 0, stream>>>(x, x16, NN * 128 / 4);
  conv_weights<<<(LL * 16384 + 262144 + 32768 + 255) / 256, 256, 0, stream>>>(
      cW1, cW2, WT1, WT2, epW1, W1T, epW2, W2T);

  for (int l = 0; l < LL; ++l) {
    const unsigned short* h16 = (l == 0) ? x16 : (emb16 + (size_t)(l - 1) * 128);
    int ld = (l == 0) ? 128 : 512;
    aggregate_bf16<<<(NN + 15) / 16, 256, 0, stream>>>(h16, ld, rowptr, csr_src, ceps + l, g16a, NN);
    trunk_fused<<<(NN + 127) / 128, 256, 0, stream>>>(
        g16a, WT1 + (size_t)l * 16384, cb1 + l * 128,
        WT2 + (size_t)l * 16384, cb2 + l * 128,
        bnsum + l * 128, bnsumsq + l * 128, g16a, NN);
    bn_apply_bf16<<<(NN * 16 + 255) / 256, 256, 0, stream>>>(
        g16a, bnsum + l * 128, bnsumsq + l * 128, cgamma + l * 128, cbeta + l * 128,
        emb16 + (size_t)l * 128, NN);
  }

  bounds_kernel<<<1, 128, 0, stream>>>(batch, gstart, NN);
  pool_bf16<<<dim3(GG, 8), 256, 0, stream>>>(emb16, gstart, gsum);
  nc_fused<<<GG, 256, 0, stream>>>(gsum, gstart, ncW1, ncb1, ncW2, ncb2, ncW3, ncb3,
                                   ncW4, ncb4, (float*)d_out);

  ep_gemm1_stream<<<(NC + 127) / 128, 512, 0, stream>>>(emb16, cand, W1T, epb1, C1, NC);
  mfma_gemm_bt<<<dim3((NC + 127) / 128, 1), 256, 0, stream>>>(C1, 256, W2T, 256, epb2, C2, 128, NC);
  ep_final_bf16<<<(NC + 3) / 4, 256, 0, stream>>>(C2, epW3, epb3, (float*)d_out + GG * CCLS, NC);
}

// Round 12
// 1117.862 us; speedup vs baseline: 1.1499x; 1.1499x over previous
//
#include <hip/hip_runtime.h>
#include <math.h>

#define NN 100000
#define EE 1600000
#define GG 64
#define HH 128
#define LL 4
#define CCLS 16
#define NC 100000
#define NB 49    // dst buckets of 2048 nodes
#define LDK 40   // padded LDS row stride (bf16 elems) for 32-wide K tiles
#define LDA2 136 // padded LDS row stride for full-K (128) A tiles

typedef __attribute__((ext_vector_type(8))) short bf16x8;
typedef __attribute__((ext_vector_type(4))) float f32x4;

__device__ __forceinline__ unsigned short f2bf(float x) {
  union { float f; unsigned int u; } v; v.f = x;
  unsigned int r = v.u + 0x7fffu + ((v.u >> 16) & 1u);
  return (unsigned short)(r >> 16);
}
__device__ __forceinline__ float bl(unsigned u) {
  union { unsigned u; float f; } v; v.u = u << 16; return v.f;
}
__device__ __forceinline__ float bh(unsigned u) {
  union { unsigned u; float f; } v; v.u = u & 0xffff0000u; return v.f;
}

// ---------------- CSR build ----------------
__global__ void hist_kernel(const int* __restrict__ dst, int* __restrict__ cnt, int E) {
  int e = blockIdx.x * 256 + threadIdx.x;
  if (e < E) atomicAdd(&cnt[dst[e]], 1);
}

__global__ __launch_bounds__(256) void scan_p1(const int* __restrict__ cnt,
                                               int* __restrict__ bsum, int n) {
  __shared__ int red[256];
  int tid = threadIdx.x;
  int base = blockIdx.x * 1024 + tid * 4;
  int s = 0;
  if (base + 3 < n) {
    int4 v = *(const int4*)(cnt + base);
    s = v.x + v.y + v.z + v.w;
  } else {
    for (int i = 0; i < 4; ++i) if (base + i < n) s += cnt[base + i];
  }
  red[tid] = s;
  __syncthreads();
  for (int st = 128; st >= 1; st >>= 1) {
    if (tid < st) red[tid] += red[tid + st];
    __syncthreads();
  }
  if (tid == 0) bsum[blockIdx.x] = red[0];
}

__global__ void scan_p2(int* __restrict__ bsum, int* __restrict__ rowptr,
                        int* __restrict__ bcursor, int nb, int n) {
  __shared__ int buf[128];
  int tid = threadIdx.x;
  int v = (tid < nb) ? bsum[tid] : 0;
  buf[tid] = v;
  __syncthreads();
  for (int off = 1; off < 128; off <<= 1) {
    int t = (tid >= off) ? buf[tid - off] : 0;
    __syncthreads();
    buf[tid] += t;
    __syncthreads();
  }
  if (tid < nb) bsum[tid] = buf[tid] - v;
  if (tid == 127) rowptr[n] = buf[127];
  __syncthreads();
  if (tid < NB) bcursor[tid] = bsum[2 * tid];
}

__global__ __launch_bounds__(256) void scan_p3(const int* __restrict__ cnt,
                                               const int* __restrict__ bsum,
                                               int* __restrict__ rowptr,
                                               int* __restrict__ cursor, int n) {
  __shared__ int red[256];
  int tid = threadIdx.x;
  int base = blockIdx.x * 1024 + tid * 4;
  int v[4] = {0, 0, 0, 0};
  if (base + 3 < n) {
    int4 t = *(const int4*)(cnt + base);
    v[0] = t.x; v[1] = t.y; v[2] = t.z; v[3] = t.w;
  } else {
    for (int i = 0; i < 4; ++i) if (base + i < n) v[i] = cnt[base + i];
  }
  int s = v[0] + v[1] + v[2] + v[3];
  red[tid] = s;
  __syncthreads();
  for (int off = 1; off < 256; off <<= 1) {
    int t = (tid >= off) ? red[tid - off] : 0;
    __syncthreads();
    red[tid] += t;
    __syncthreads();
  }
  int run = bsum[blockIdx.x] + red[tid] - s;
  int4 o;
  o.x = run; o.y = run + v[0]; o.z = o.y + v[1]; o.w = o.z + v[2];
  if (base + 3 < n) {
    *(int4*)(rowptr + base) = o;
    *(int4*)(cursor + base) = o;
  } else {
    int oo[4] = {o.x, o.y, o.z, o.w};
    for (int i = 0; i < 4; ++i)
      if (base + i < n) { rowptr[base + i] = oo[i]; cursor[base + i] = oo[i]; }
  }
}

// Counting-sort pass 1: partition edges into 49 dst-bucket pair regions.
__global__ __launch_bounds__(256) void partition_kernel(const int* __restrict__ src,
                                                        const int* __restrict__ dst,
                                                        int* __restrict__ bcursor,
                                                        int2* __restrict__ pairs, int E) {
  __shared__ int sS[4096];
  __shared__ int sD[4096];
  __shared__ int hist[NB];
  __shared__ int base[NB];
  int tid = threadIdx.x;
  int base_e = blockIdx.x * 4096;
  int cnt = min(4096, E - base_e);
  if (tid < NB) hist[tid] = 0;
  for (int i = tid * 4; i < cnt; i += 1024) {
    if (i + 3 < cnt) {
      *(int4*)(sS + i) = *(const int4*)(src + base_e + i);
      *(int4*)(sD + i) = *(const int4*)(dst + base_e + i);
    } else {
      for (int k = i; k < cnt; ++k) { sS[k] = src[base_e + k]; sD[k] = dst[base_e + k]; }
    }
  }
  __syncthreads();
  for (int i = tid; i < cnt; i += 256) atomicAdd(&hist[sD[i] >> 11], 1);
  __syncthreads();
  if (tid < NB) {
    base[tid] = atomicAdd(&bcursor[tid], hist[tid]);
    hist[tid] = 0;
  }
  __syncthreads();
  for (int i = tid; i < cnt; i += 256) {
    int d = sD[i];
    int b = d >> 11;
    int off = atomicAdd(&hist[b], 1);
    pairs[base[b] + off] = make_int2(sS[i], d);
  }
}

// Counting-sort pass 2: per-bucket scatter to final CSR positions.
__global__ __launch_bounds__(256) void scatter_csr(const int2* __restrict__ pairs,
                                                   const int* __restrict__ rowptr,
                                                   int* __restrict__ cursor,
                                                   int* __restrict__ csr_src) {
  int b = blockIdx.x % 56;
  int slice = blockIdx.x / 56;
  if (b >= NB) return;
  int start = rowptr[b * 2048];
  int endn = min((b + 1) * 2048, NN);
  int end = rowptr[endn];
  for (int i = start + slice * 256 + threadIdx.x; i < end; i += 8 * 256) {
    int2 p = pairs[i];
    int pos = atomicAdd(&cursor[p.y], 1);
    csr_src[pos] = p.x;
  }
}

// ---------------- converts ----------------
__global__ void f2b4_kernel(const float* __restrict__ in, unsigned short* __restrict__ out, int n4) {
  int i = blockIdx.x * 256 + threadIdx.x;
  if (i >= n4) return;
  float4 v = ((const float4*)in)[i];
  unsigned short r[4] = {f2bf(v.x), f2bf(v.y), f2bf(v.z), f2bf(v.w)};
  *(uint2*)(out + (size_t)i * 4) = *(uint2*)r;
}

// merged: trunk W1/W2, epW1, epW2 — all to [N][K] bf16
__global__ void conv_weights(const float* __restrict__ cW1, const float* __restrict__ cW2,
                             unsigned short* __restrict__ WT1, unsigned short* __restrict__ WT2,
                             const float* __restrict__ epW1, unsigned short* __restrict__ W1T,
                             const float* __restrict__ epW2, unsigned short* __restrict__ W2T) {
  int idx = blockIdx.x * 256 + threadIdx.x;
  if (idx < LL * 16384) {
    int l = idx >> 14, r = idx & 16383, k = r >> 7, n = r & 127;
    WT1[l * 16384 + n * 128 + k] = f2bf(cW1[idx]);
    WT2[l * 16384 + n * 128 + k] = f2bf(cW2[idx]);
  } else if (idx < LL * 16384 + 262144) {
    int j = idx - LL * 16384;
    int k = j >> 8, n = j & 255;
    W1T[(size_t)n * 1024 + k] = f2bf(epW1[j]);
  } else if (idx < LL * 16384 + 262144 + 32768) {
    int j = idx - LL * 16384 - 262144;
    int k = j >> 7, n = j & 127;
    W2T[(size_t)n * 256 + k] = f2bf(epW2[j]);
  }
}

// ---------------- GIN aggregate: 16-lane subgroup per node, x8 unroll ----------------
__global__ void aggregate_bf16(const unsigned short* __restrict__ h16, int ld,
                               const int* __restrict__ rowptr,
                               const int* __restrict__ csr_src,
                               const float* __restrict__ ceps_l,
                               unsigned short* __restrict__ out, int n) {
  int wave = threadIdx.x >> 6;
  int lane = threadIdx.x & 63;
  int sub = lane >> 4;
  int li = lane & 15;
  int node = blockIdx.x * 16 + wave * 4 + sub;
  if (node >= n) return;
  int c8 = li * 8;
  float eps1 = 1.0f + *ceps_l;
  float acc[8] = {};
  int b = rowptr[node], e = rowptr[node + 1];
  int j = b;
  for (; j + 8 <= e; j += 8) {
    uint4 u[8];
#pragma unroll
    for (int t = 0; t < 8; ++t) {
      int s = csr_src[j + t];
      u[t] = *(const uint4*)(h16 + (size_t)s * ld + c8);
    }
#pragma unroll
    for (int t = 0; t < 8; ++t) {
      acc[0] += bl(u[t].x); acc[1] += bh(u[t].x);
      acc[2] += bl(u[t].y); acc[3] += bh(u[t].y);
      acc[4] += bl(u[t].z); acc[5] += bh(u[t].z);
      acc[6] += bl(u[t].w); acc[7] += bh(u[t].w);
    }
  }
  for (; j < e; ++j) {
    int s = csr_src[j];
    uint4 u = *(const uint4*)(h16 + (size_t)s * ld + c8);
    acc[0] += bl(u.x); acc[1] += bh(u.x);
    acc[2] += bl(u.y); acc[3] += bh(u.y);
    acc[4] += bl(u.z); acc[5] += bh(u.z);
    acc[6] += bl(u.w); acc[7] += bh(u.w);
  }
  uint4 hu = *(const uint4*)(h16 + (size_t)node * ld + c8);
  acc[0] = fmaf(eps1, bl(hu.x), acc[0]); acc[1] = fmaf(eps1, bh(hu.x), acc[1]);
  acc[2] = fmaf(eps1, bl(hu.y), acc[2]); acc[3] = fmaf(eps1, bh(hu.y), acc[3]);
  acc[4] = fmaf(eps1, bl(hu.z), acc[4]); acc[5] = fmaf(eps1, bh(hu.z), acc[5]);
  acc[6] = fmaf(eps1, bl(hu.w), acc[6]); acc[7] = fmaf(eps1, bh(hu.w), acc[7]);
  unsigned short o[8];
#pragma unroll
  for (int i = 0; i < 8; ++i) o[i] = f2bf(acc[i]);
  *(uint4*)(out + (size_t)node * 128 + c8) = *(uint4*)o;
}

// ---------------- fused trunk layer (B register-prefetch) ----------------
__global__ __launch_bounds__(256) void trunk_fused(
    const unsigned short* __restrict__ A16,
    const unsigned short* __restrict__ W1T, const float* __restrict__ b1,
    const unsigned short* __restrict__ W2T, const float* __restrict__ b2,
    float* __restrict__ bnsum, float* __restrict__ bnsumsq,
    unsigned short* __restrict__ C16, int M) {
  __shared__ unsigned short As[128 * LDA2];
  __shared__ unsigned short Bs[128 * LDK];
  const int tid = threadIdx.x;
  const int bm = blockIdx.x * 128;
  const int lane = tid & 63;
  const int wave = tid >> 6;
  const int wr = (wave >> 1) << 6;
  const int wc = (wave & 1) << 6;
  const int ar = tid >> 1;
  const int ah = (tid & 1) << 4;
  int gra = bm + ar; if (gra >= M) gra = M - 1;
  const unsigned short* Arow = A16 + (size_t)gra * 128;
  const int mrow = lane & 15;
  const int kq = (lane >> 4) << 3;
  f32x4 acc[4][4] = {};

#pragma unroll
  for (int ks = 0; ks < 4; ++ks) {
    const int k0 = ks << 5;
    const uint4* s = (const uint4*)(Arow + k0 + ah);
    *(uint4*)(As + ar * LDA2 + k0 + ah) = s[0];
    *(uint4*)(As + ar * LDA2 + k0 + ah + 8) = s[1];
  }
  uint4 p0 = *(const uint4*)(W1T + (size_t)ar * 128 + ah);
  uint4 p1 = *(const uint4*)(W1T + (size_t)ar * 128 + ah + 8);
  for (int ks = 0; ks < 4; ++ks) {
    const int k0 = ks << 5;
    *(uint4*)(Bs + ar * LDK + ah) = p0;
    *(uint4*)(Bs + ar * LDK + ah + 8) = p1;
    __syncthreads();
    if (ks < 3) {
      p0 = *(const uint4*)(W1T + (size_t)ar * 128 + k0 + 32 + ah);
      p1 = *(const uint4*)(W1T + (size_t)ar * 128 + k0 + 32 + ah + 8);
    }
    bf16x8 af[4], bfv[4];
#pragma unroll
    for (int t = 0; t < 4; ++t)
      af[t] = *(const bf16x8*)(As + (wr + t * 16 + mrow) * LDA2 + k0 + kq);
#pragma unroll
    for (int t = 0; t < 4; ++t)
      bfv[t] = *(const bf16x8*)(Bs + (wc + t * 16 + mrow) * LDK + kq);
#pragma unroll
    for (int mt = 0; mt < 4; ++mt)
#pragma unroll
      for (int nt = 0; nt < 4; ++nt)
        acc[mt][nt] = __builtin_amdgcn_mfma_f32_16x16x32_bf16(af[mt], bfv[nt], acc[mt][nt], 0, 0, 0);
    __syncthreads();
  }
  const int crow = (lane >> 4) << 2;
  const int ccol = lane & 15;
#pragma unroll
  for (int nt = 0; nt < 4; ++nt) {
    int c = wc + nt * 16 + ccol;
    float bz = b1[c];
#pragma unroll
    for (int mt = 0; mt < 4; ++mt) {
      int rl = wr + mt * 16 + crow;
#pragma unroll
      for (int i = 0; i < 4; ++i)
        As[(rl + i) * LDA2 + c] = f2bf(fmaxf(acc[mt][nt][i] + bz, 0.f));
    }
  }
#pragma unroll
  for (int mt = 0; mt < 4; ++mt)
#pragma unroll
    for (int nt = 0; nt < 4; ++nt)
      acc[mt][nt] = (f32x4){0.f, 0.f, 0.f, 0.f};
  p0 = *(const uint4*)(W2T + (size_t)ar * 128 + ah);
  p1 = *(const uint4*)(W2T + (size_t)ar * 128 + ah + 8);
  __syncthreads();
  for (int ks = 0; ks < 4; ++ks) {
    const int k0 = ks << 5;
    *(uint4*)(Bs + ar * LDK + ah) = p0;
    *(uint4*)(Bs + ar * LDK + ah + 8) = p1;
    __syncthreads();
    if (ks < 3) {
      p0 = *(const uint4*)(W2T + (size_t)ar * 128 + k0 + 32 + ah);
      p1 = *(const uint4*)(W2T + (size_t)ar * 128 + k0 + 32 + ah + 8);
    }
    bf16x8 af[4], bfv[4];
#pragma unroll
    for (int t = 0; t < 4; ++t)
      af[t] = *(const bf16x8*)(As + (wr + t * 16 + mrow) * LDA2 + k0 + kq);
#pragma unroll
    for (int t = 0; t < 4; ++t)
      bfv[t] = *(const bf16x8*)(Bs + (wc + t * 16 + mrow) * LDK + kq);
#pragma unroll
    for (int mt = 0; mt < 4; ++mt)
#pragma unroll
      for (int nt = 0; nt < 4; ++nt)
        acc[mt][nt] = __builtin_amdgcn_mfma_f32_16x16x32_bf16(af[mt], bfv[nt], acc[mt][nt], 0, 0, 0);
    __syncthreads();
  }
#pragma unroll
  for (int nt = 0; nt < 4; ++nt) {
    int c = wc + nt * 16 + ccol;
    float bz = b2[c];
    float s = 0.f, q = 0.f;
#pragma unroll
    for (int mt = 0; mt < 4; ++mt) {
      int rbase = bm + wr + mt * 16 + crow;
#pragma unroll
      for (int i = 0; i < 4; ++i) {
        int r = rbase + i;
        if (r < M) {
          float v = fmaxf(acc[mt][nt][i] + bz, 0.f);
          C16[(size_t)r * 128 + c] = f2bf(v);
          s += v; q += v * v;
        }
      }
    }
    s += __shfl_xor(s, 16, 64);
    s += __shfl_xor(s, 32, 64);
    q += __shfl_xor(q, 16, 64);
    q += __shfl_xor(q, 32, 64);
    if (lane < 16) {
      atomicAdd(&bnsum[c], s);
      atomicAdd(&bnsumsq[c], q);
    }
  }
}

// ep GEMM1 with fused candidate gather: double-buffered LDS, one barrier/step.
// (R8 version — best measured structure for the random-gather GEMM, ~112 µs.)
__global__ __launch_bounds__(512) void mfma_gemm_gather(
    const unsigned short* __restrict__ emb16, const int* __restrict__ cand,
    const unsigned short* __restrict__ WT /*[256][1024]*/,
    const float* __restrict__ bias,
    unsigned short* __restrict__ C16 /*[M,256]*/, int M) {
  __shared__ unsigned short As[2][128 * LDK];
  __shared__ unsigned short Bs[2][256 * LDK];
  const int tid = threadIdx.x;
  const int bm = blockIdx.x * 128;
  const int lane = tid & 63;
  const int wave = tid >> 6;
  const int wr = (wave >> 2) << 6;
  const int wc = (wave & 3) << 6;
  f32x4 acc[4][4] = {};
  const int ar = tid >> 2;
  const int ah = (tid & 3) << 3;
  int gra = bm + ar; if (gra >= M) gra = M - 1;
  const int node0 = cand[gra];
  const int node1 = cand[NC + gra];
  const int br = tid >> 1;
  const int bh8 = (tid & 1) << 4;
  const unsigned short* Brow = WT + (size_t)br * 1024 + bh8;
  const int mrow = lane & 15;
  const int kq = (lane >> 4) << 3;

  {
    uint4 a = *(const uint4*)(emb16 + (size_t)node0 * 512 + ah);
    uint4 b0 = *(const uint4*)(Brow);
    uint4 b1 = *(const uint4*)(Brow + 8);
    *(uint4*)(As[0] + ar * LDK + ah) = a;
    *(uint4*)(Bs[0] + br * LDK + bh8) = b0;
    *(uint4*)(Bs[0] + br * LDK + bh8 + 8) = b1;
  }
  __syncthreads();
  for (int ks = 0; ks < 32; ++ks) {
    const int cur = ks & 1, nxt = cur ^ 1;
    uint4 a, b0, b1;
    if (ks < 31) {
      const int k1 = (ks + 1) << 5;
      int node = (k1 < 512) ? node0 : node1;
      a = *(const uint4*)(emb16 + (size_t)node * 512 + (k1 & 511) + ah);
      b0 = *(const uint4*)(Brow + k1);
      b1 = *(const uint4*)(Brow + k1 + 8);
    }
    bf16x8 af[4], bfv[4];
#pragma unroll
    for (int t = 0; t < 4; ++t)
      af[t] = *(const bf16x8*)(As[cur] + (wr + t * 16 + mrow) * LDK + kq);
#pragma unroll
    for (int t = 0; t < 4; ++t)
      bfv[t] = *(const bf16x8*)(Bs[cur] + (wc + t * 16 + mrow) * LDK + kq);
#pragma unroll
    for (int mt = 0; mt < 4; ++mt)
#pragma unroll
      for (int nt = 0; nt < 4; ++nt)
        acc[mt][nt] = __builtin_amdgcn_mfma_f32_16x16x32_bf16(af[mt], bfv[nt], acc[mt][nt], 0, 0, 0);
    if (ks < 31) {
      *(uint4*)(As[nxt] + ar * LDK + ah) = a;
      *(uint4*)(Bs[nxt] + br * LDK + bh8) = b0;
      *(uint4*)(Bs[nxt] + br * LDK + bh8 + 8) = b1;
      __syncthreads();
    }
  }
  const int crow = (lane >> 4) << 2;
  const int ccol = lane & 15;
#pragma unroll
  for (int nt = 0; nt < 4; ++nt) {
    int cbase = wc + nt * 16 + ccol;
    float bz = bias[cbase];
#pragma unroll
    for (int mt = 0; mt < 4; ++mt) {
      int rbase = bm + wr + mt * 16 + crow;
#pragma unroll
      for (int i = 0; i < 4; ++i) {
        int r = rbase + i;
        if (r < M) C16[(size_t)r * 256 + cbase] = f2bf(fmaxf(acc[mt][nt][i] + bz, 0.f));
      }
    }
  }
}

// ep GEMM2 + final fused: C2 = relu(C1 @ W2T^T + b2) stays in registers;
// epilogue computes edge_scores = sigmoid(C2 . epW3 + epb3) via LDS reduction.
// C2 never touches global memory.
__global__ __launch_bounds__(256) void ep_gemm2_final(
    const unsigned short* __restrict__ A16 /* C1 [M,256] */,
    const unsigned short* __restrict__ WT /* W2T [128][256] */,
    const float* __restrict__ b2, const float* __restrict__ epW3,
    const float* __restrict__ epb3,
    float* __restrict__ out, int M) {
  __shared__ unsigned short As[2][128 * LDK];
  __shared__ unsigned short Bs[2][128 * LDK];
  __shared__ float sDot[128];
  const int tid = threadIdx.x;
  const int bm = blockIdx.x * 128;
  const int lane = tid & 63;
  const int wave = tid >> 6;
  const int wr = (wave >> 1) << 6;
  const int wc = (wave & 1) << 6;
  f32x4 acc[4][4] = {};
  const int ar = tid >> 1;
  const int ah = (tid & 1) << 4;
  int gra = bm + ar; if (gra >= M) gra = M - 1;
  const unsigned short* Arow = A16 + (size_t)gra * 256;
  const unsigned short* Brow = WT + (size_t)ar * 256;
  const int mrow = lane & 15;
  const int kq = (lane >> 4) << 3;

  if (tid < 128) sDot[tid] = 0.f;
  {
    uint4 a0 = *(const uint4*)(Arow + ah);
    uint4 a1 = *(const uint4*)(Arow + ah + 8);
    uint4 b0 = *(const uint4*)(Brow + ah);
    uint4 b1 = *(const uint4*)(Brow + ah + 8);
    *(uint4*)(As[0] + ar * LDK + ah) = a0;
    *(uint4*)(As[0] + ar * LDK + ah + 8) = a1;
    *(uint4*)(Bs[0] + ar * LDK + ah) = b0;
    *(uint4*)(Bs[0] + ar * LDK + ah + 8) = b1;
  }
  __syncthreads();
  for (int ks = 0; ks < 8; ++ks) {
    const int cur = ks & 1, nxt = cur ^ 1;
    uint4 a0, a1, b0, b1;
    if (ks < 7) {
      const int k1 = (ks + 1) << 5;
      a0 = *(const uint4*)(Arow + k1 + ah);
      a1 = *(const uint4*)(Arow + k1 + ah + 8);
      b0 = *(const uint4*)(Brow + k1 + ah);
      b1 = *(const uint4*)(Brow + k1 + ah + 8);
    }
    bf16x8 af[4], bfv[4];
#pragma unroll
    for (int t = 0; t < 4; ++t)
      af[t] = *(const bf16x8*)(As[cur] + (wr + t * 16 + mrow) * LDK + kq);
#pragma unroll
    for (int t = 0; t < 4; ++t)
      bfv[t] = *(const bf16x8*)(Bs[cur] + (wc + t * 16 + mrow) * LDK + kq);
#pragma unroll
    for (int mt = 0; mt < 4; ++mt)
#pragma unroll
      for (int nt = 0; nt < 4; ++nt)
        acc[mt][nt] = __builtin_amdgcn_mfma_f32_16x16x32_bf16(af[mt], bfv[nt], acc[mt][nt], 0, 0, 0);
    if (ks < 7) {
      *(uint4*)(As[nxt] + ar * LDK + ah) = a0;
      *(uint4*)(As[nxt] + ar * LDK + ah + 8) = a1;
      *(uint4*)(Bs[nxt] + ar * LDK + ah) = b0;
      *(uint4*)(Bs[nxt] + ar * LDK + ah + 8) = b1;
      __syncthreads();
    }
  }
  // epilogue: per-lane partial dot with epW3 over this lane's 4 cols, per row
  const int crow = (lane >> 4) << 2;
  const int ccol = lane & 15;
  float w3v[4], bz[4];
#pragma unroll
  for (int nt = 0; nt < 4; ++nt) {
    int c = wc + nt * 16 + ccol;
    w3v[nt] = epW3[c];
    bz[nt] = b2[c];
  }
  __syncthreads();  // sDot init visible; K-loop done
#pragma unroll
  for (int mt = 0; mt < 4; ++mt) {
#pragma unroll
    for (int i = 0; i < 4; ++i) {
      int rl = wr + mt * 16 + crow + i;
      float p = 0.f;
#pragma unroll
      for (int nt = 0; nt < 4; ++nt)
        p = fmaf(fmaxf(acc[mt][nt][i] + bz[nt], 0.f), w3v[nt], p);
      atomicAdd(&sDot[rl], p);
    }
  }
  __syncthreads();
  if (tid < 128) {
    int r = bm + tid;
    if (r < M) out[r] = 1.f / (1.f + expf(-(sDot[tid] + epb3[0])));
  }
}

// ---------------- BatchNorm apply ----------------
__global__ void bn_apply_bf16(const unsigned short* __restrict__ z,
                              const float* __restrict__ sum, const float* __restrict__ sumsq,
                              const float* __restrict__ gamma, const float* __restrict__ beta,
                              unsigned short* __restrict__ out, int n) {
  int idx = blockIdx.x * 256 + threadIdx.x;
  if (idx >= n * 16) return;
  int r = idx >> 4, c8 = (idx & 15) << 3;
  uint4 v = *(const uint4*)(z + (size_t)r * 128 + c8);
  float f[8] = {bl(v.x), bh(v.x), bl(v.y), bh(v.y), bl(v.z), bh(v.z), bl(v.w), bh(v.w)};
  const float inv_n = 1.0f / (float)NN;
  unsigned short o[8];
#pragma unroll
  for (int j = 0; j < 8; ++j) {
    int c = c8 + j;
    float mu = sum[c] * inv_n;
    float var = sumsq[c] * inv_n - mu * mu;
    float sc = rsqrtf(var + 1e-5f) * gamma[c];
    o[j] = f2bf((f[j] - mu) * sc + beta[c]);
  }
  *(uint4*)(out + (size_t)r * 512 + c8) = *(uint4*)o;
}

// ---------------- pooling ----------------
__global__ void bounds_kernel(const int* __restrict__ batch, int* __restrict__ gstart, int n) {
  int g = threadIdx.x;
  if (g > GG) return;
  int lo = 0, hi = n;
  while (lo < hi) {
    int mid = (lo + hi) >> 1;
    if (batch[mid] < g) lo = mid + 1; else hi = mid;
  }
  gstart[g] = lo;
}

__global__ __launch_bounds__(256) void pool_bf16(const unsigned short* __restrict__ emb16,
                                                 const int* __restrict__ gstart,
                                                 float* __restrict__ gsum) {
  int g = blockIdx.x;
  int chunk = blockIdx.y;
  int c2 = threadIdx.x * 2;
  int s = gstart[g], e = gstart[g + 1];
  int len = e - s;
  int per = (len + 7) >> 3;
  int r0 = s + chunk * per;
  int r1 = min(r0 + per, e);
  float ax = 0.f, ay = 0.f;
  for (int r = r0; r < r1; ++r) {
    unsigned u = *(const unsigned*)(emb16 + (size_t)r * 512 + c2);
    ax += bl(u); ay += bh(u);
  }
  if (r1 > r0) {
    atomicAdd(&gsum[g * 512 + c2], ax);
    atomicAdd(&gsum[g * 512 + c2 + 1], ay);
  }
}

// ---------------- fused node classifier ----------------
__global__ __launch_bounds__(256) void nc_fused(
    const float* __restrict__ gsum, const int* __restrict__ gstart,
    const float* __restrict__ W1, const float* __restrict__ b1,
    const float* __restrict__ W2, const float* __restrict__ b2,
    const float* __restrict__ W3, const float* __restrict__ b3,
    const float* __restrict__ W4, const float* __restrict__ b4,
    float* __restrict__ out) {
  __shared__ float row[512];
  __shared__ float t1[256];
  __shared__ float t2[128];
  __shared__ float t3s[128];
  __shared__ float lg[16];
  int g = blockIdx.x;
  int tid = threadIdx.x;
  float inv = 1.0f / fmaxf((float)(gstart[g + 1] - gstart[g]), 1.0f);
  row[tid] = gsum[g * 512 + tid] * inv;
  row[tid + 256] = gsum[g * 512 + tid + 256] * inv;
  __syncthreads();
  {
    float acc = b1[tid];
#pragma unroll 8
    for (int k = 0; k < 512; ++k) acc = fmaf(row[k], W1[k * 256 + tid], acc);
    t1[tid] = fmaxf(acc, 0.f);
  }
  __syncthreads();
  if (tid < 128) {
    float acc = b2[tid];
#pragma unroll 8
    for (int k = 0; k < 256; ++k) acc = fmaf(t1[k], W2[k * 128 + tid], acc);
    t2[tid] = fmaxf(acc, 0.f);
  }
  __syncthreads();
  if (tid < 128) {
    float acc = b3[tid];
#pragma unroll 8
    for (int k = 0; k < 128; ++k) acc = fmaf(t2[k], W3[k * 128 + tid], acc);
    t3s[tid] = fmaxf(acc, 0.f);
  }
  __syncthreads();
  if (tid < 16) {
    float acc = b4[tid];
#pragma unroll 8
    for (int k = 0; k < 128; ++k) acc = fmaf(t3s[k], W4[k * 16 + tid], acc);
    lg[tid] = acc;
  }
  __syncthreads();
  if (tid < 16) {
    float v = lg[tid];
    float m = v;
    for (int j = 0; j < 16; ++j) m = fmaxf(m, lg[j]);
    float s = 0.f;
    for (int j = 0; j < 16; ++j) s += expf(lg[j] - m);
    out[g * 16 + tid] = v - m - logf(s);
  }
}

// ---------------- launch ----------------
extern "C" void kernel_launch(void* const* d_in, const int* in_sizes, int n_in,
                              void* d_out, int out_size, void* d_ws, size_t ws_size,
                              hipStream_t stream) {
  const float* x = (const float*)d_in[0];
  const int* edge_index = (const int*)d_in[1];
  const int* batch = (const int*)d_in[2];
  const int* cand = (const int*)d_in[3];
  const float* cW1 = (const float*)d_in[4];
  const float* cb1 = (const float*)d_in[5];
  const float* cW2 = (const float*)d_in[6];
  const float* cb2 = (const float*)d_in[7];
  const float* cgamma = (const float*)d_in[8];
  const float* cbeta = (const float*)d_in[9];
  const float* ceps = (const float*)d_in[10];
  const float* ncW1 = (const float*)d_in[11];
  const float* ncb1 = (const float*)d_in[12];
  const float* ncW2 = (const float*)d_in[13];
  const float* ncb2 = (const float*)d_in[14];
  const float* ncW3 = (const float*)d_in[15];
  const float* ncb3 = (const float*)d_in[16];
  const float* ncW4 = (const float*)d_in[17];
  const float* ncb4 = (const float*)d_in[18];
  const float* epW1 = (const float*)d_in[19];
  const float* epb1 = (const float*)d_in[20];
  const float* epW2 = (const float*)d_in[21];
  const float* epb2 = (const float*)d_in[22];
  const float* epW3 = (const float*)d_in[23];
  const float* epb3 = (const float*)d_in[24];

  char* ws = (char*)d_ws;
  size_t off = 0;
  auto alloc = [&](size_t bytes) -> void* {
    off = (off + 255) & ~(size_t)255;
    void* p = ws + off;
    off += bytes;
    return p;
  };
  // zero zone: cnt | bnsum | bnsumsq | gsum
  size_t zz_bytes = (size_t)NN * 4 + 512 * 4 + 512 * 4 + (size_t)GG * 512 * 4;
  char* zz = (char*)alloc(zz_bytes);
  int* cnt = (int*)zz;
  float* bnsum = (float*)(zz + (size_t)NN * 4);
  float* bnsumsq = bnsum + 512;
  float* gsum = bnsumsq + 512;
  int* rowptr = (int*)alloc((size_t)(NN + 1) * 4);
  int* cursor = (int*)alloc((size_t)NN * 4);
  int* csr_src = (int*)alloc((size_t)EE * 4);
  int2* pairs = (int2*)alloc((size_t)EE * 8);
  int* bsum = (int*)alloc(128 * 4);
  int* bcursor = (int*)alloc(64 * 4);
  unsigned short* x16 = (unsigned short*)alloc((size_t)NN * 128 * 2);
  unsigned short* g16a = (unsigned short*)alloc((size_t)NN * 128 * 2);
  unsigned short* emb16 = (unsigned short*)alloc((size_t)NN * 512 * 2);
  unsigned short* C1 = (unsigned short*)alloc((size_t)NC * 256 * 2);
  unsigned short* WT1 = (unsigned short*)alloc((size_t)LL * 16384 * 2);
  unsigned short* WT2 = (unsigned short*)alloc((size_t)LL * 16384 * 2);
  unsigned short* W1T = (unsigned short*)alloc((size_t)1024 * 256 * 2);
  unsigned short* W2T = (unsigned short*)alloc((size_t)256 * 128 * 2);
  int* gstart = (int*)alloc(65 * 4);

  const int* esrc = edge_index;
  const int* edst = edge_index + EE;
  const int nblk = (NN + 1023) / 1024;   // 98
  const int nech = (EE + 4095) / 4096;   // 391

  hipMemsetAsync(zz, 0, zz_bytes, stream);
  hist_kernel<<<(EE + 255) / 256, 256, 0, stream>>>(edst, cnt, EE);
  scan_p1<<<nblk, 256, 0, stream>>>(cnt, bsum, NN);
  scan_p2<<<1, 128, 0, stream>>>(bsum, rowptr, bcursor, nblk, NN);
  scan_p3<<<nblk, 256, 0, stream>>>(cnt, bsum, rowptr, cursor, NN);
  partition_kernel<<<nech, 256, 0, stream>>>(esrc, edst, bcursor, pairs, EE);
  scatter_csr<<<56 * 8, 256, 0, stream>>>(pairs, rowptr, cursor, csr_src);
  f2b4_kernel<<<(NN * 128 / 4 + 255) / 256, 256, 0, stream>>>(x, x16, NN * 128 / 4);
  conv_weights<<<(LL * 16384 + 262144 + 32768 + 255) / 256, 256, 0, stream>>>(
      cW1, cW2, WT1, WT2, epW1, W1T, epW2, W2T);

  for (int l = 0; l < LL; ++l) {
    const unsigned short* h16 = (l == 0) ? x16 : (emb16 + (size_t)(l - 1) * 128);
    int ld = (l == 0) ? 128 : 512;
    aggregate_bf16<<<(NN + 15) / 16, 256, 0, stream>>>(h16, ld, rowptr, csr_src, ceps + l, g16a, NN);
    trunk_fused<<<(NN + 127) / 128, 256, 0, stream>>>(
        g16a, WT1 + (size_t)l * 16384, cb1 + l * 128,
        WT2 + (size_t)l * 16384, cb2 + l * 128,
        bnsum + l * 128, bnsumsq + l * 128, g16a, NN);
    bn_apply_bf16<<<(NN * 16 + 255) / 256, 256, 0, stream>>>(
        g16a, bnsum + l * 128, bnsumsq + l * 128, cgamma + l * 128, cbeta + l * 128,
        emb16 + (size_t)l * 128, NN);
  }

  bounds_kernel<<<1, 128, 0, stream>>>(batch, gstart, NN);
  pool_bf16<<<dim3(GG, 8), 256, 0, stream>>>(emb16, gstart, gsum);
  nc_fused<<<GG, 256, 0, stream>>>(gsum, gstart, ncW1, ncb1, ncW2, ncb2, ncW3, ncb3,
                                   ncW4, ncb4, (float*)d_out);

  mfma_gemm_gather<<<(NC + 127) / 128, 512, 0, stream>>>(emb16, cand, W1T, epb1, C1, NC);
  ep_gemm2_final<<<(NC + 127) / 128, 256, 0, stream>>>(C1, W2T, epb2, epW3, epb3,
                                                       (float*)d_out + GG * CCLS, NC);
}